// Round 2
// baseline (4308.554 us; speedup 1.0000x reference)
//
#include <hip/hip_runtime.h>

#define T_STEPS 512
#define NTHREADS 256
#define RPW 4          // k-rows per wave
#define EPSF 1e-6f
#define BASE_LR_F 0.01f

__device__ __forceinline__ float lane_bcast(float v, int l) {
    return __int_as_float(__builtin_amdgcn_readlane(__float_as_int(v), l));
}

// 64-lane sum: butterfly masks 16..1 (stay inside 32-lane halves -> ds_swizzle
// safe), then combine the two half-sums via readlane(0)+readlane(32).
// This is the cdna4_isa.md canonical reduction shape.
__device__ __forceinline__ float wave_sum1(float a) {
    #pragma unroll
    for (int m = 16; m >= 1; m >>= 1) a += __shfl_xor(a, m, 64);
    return lane_bcast(a, 0) + lane_bcast(a, 32);
}
__device__ __forceinline__ void wave_sum2(float &a, float &b) {
    #pragma unroll
    for (int m = 16; m >= 1; m >>= 1) {
        a += __shfl_xor(a, m, 64);
        b += __shfl_xor(b, m, 64);
    }
    a = lane_bcast(a, 0) + lane_bcast(a, 32);
    b = lane_bcast(b, 0) + lane_bcast(b, 32);
}

struct SMem {
    float Wsh[64][64];                    // W[d][f]
    float b1s[64];
    __align__(16) float xk[2][16][68];    // double-buffered per-step arrays
    __align__(16) float xq[2][16][68];
    float gz[2][16][68];
    float A[2][16][17];
    float eta[2][16];
    float red[2][4][64];
};

__global__ __launch_bounds__(NTHREADS) void ttt_kernel(
    const float* __restrict__ XQ, const float* __restrict__ XK,
    const float* __restrict__ XV, const float* __restrict__ W1,
    const float* __restrict__ b1, const float* __restrict__ gamma,
    const float* __restrict__ beta, float* __restrict__ OUT)
{
    __shared__ SMem sm;

    const int bh  = blockIdx.x;        // b*16 + h
    const int h   = bh & 15;
    const int tid = threadIdx.x;
    const int f   = tid & 63;
    const int w   = tid >> 6;

    // ---- zero ALL LDS (kills any dependence on stale LDS from prior kernels)
    {
        float* zp = (float*)&sm;
        const int nflt = (int)(sizeof(SMem) / 4);
        for (int i = tid; i < nflt; i += NTHREADS) zp[i] = 0.0f;
    }
    __syncthreads();

    // ---- load state: W1[h], b1[h]; gamma/beta[h] to regs ----
    for (int i = tid; i < 4096; i += NTHREADS)
        sm.Wsh[i >> 6][i & 63] = W1[h * 4096 + i];
    if (tid < 64) sm.b1s[tid] = b1[h * 64 + tid];
    const float g_f  = gamma[h * 64 + f];
    const float be_f = beta[h * 64 + f];

    const int base = bh * (T_STEPS * 1024);

    // ---- prefetch t=0 (lane f holds column f of its wave's rows) ----
    float xkr[RPW], xqr[RPW], xvr[RPW];
    float nxk[RPW], nxq[RPW], nxv[RPW];
    #pragma unroll
    for (int j = 0; j < RPW; ++j) {
        const int row = w * RPW + j;
        nxk[j] = XK[base + row * 64 + f];
        nxq[j] = XQ[base + row * 64 + f];
        nxv[j] = XV[base + row * 64 + f];
    }
    __syncthreads();

    for (int t = 0; t < T_STEPS; ++t) {
        const int p = t & 1;               // LDS buffer parity
        #pragma unroll
        for (int j = 0; j < RPW; ++j) { xkr[j]=nxk[j]; xqr[j]=nxq[j]; xvr[j]=nxv[j]; }
        if (t + 1 < T_STEPS) {             // software prefetch next step
            const int o1 = base + (t + 1) * 1024;
            #pragma unroll
            for (int j = 0; j < RPW; ++j) {
                const int row = w * RPW + j;
                nxk[j] = XK[o1 + row * 64 + f];
                nxq[j] = XQ[o1 + row * 64 + f];
                nxv[j] = XV[o1 + row * 64 + f];
            }
        }

        // ---- R0: stage xk,xq; eta per row ----
        #pragma unroll
        for (int j = 0; j < RPW; ++j) {
            const int row = w * RPW + j;
            sm.xk[p][row][f] = xkr[j];
            sm.xq[p][row][f] = xqr[j];
            const float s = wave_sum1(xkr[j] * xkr[j]);
            if (f == 0) {
                const float nrm = fmaxf(sqrtf(s), EPSF);
                sm.eta[p][row] = BASE_LR_F / (1.0f + nrm);
            }
        }
        __syncthreads();                                   // B1

        // ---- R1: em/el via broadcast reads (no reduction needed) ----
        float esum = 0.0f;
        #pragma unroll
        for (int k = 0; k < 16; ++k) esum += sm.eta[p][k];
        const float em = esum * (1.0f / 16.0f);
        const float el = sm.eta[p][15];

        // Z1 = xk @ W1c + b1c  (wave's 4 rows)
        const float bb = sm.b1s[f];
        float acc[RPW];
        #pragma unroll
        for (int j = 0; j < RPW; ++j) acc[j] = bb;
        #pragma unroll
        for (int d = 0; d < 64; ++d) {
            const float wd = sm.Wsh[d][f];
            #pragma unroll
            for (int j = 0; j < RPW; ++j)
                acc[j] = fmaf(lane_bcast(xkr[j], d), wd, acc[j]);
        }

        // ln(Z1) -> grad_Z1 ; stage gz ; partial grad_b1
        float gzp = 0.0f;
        #pragma unroll
        for (int j = 0; j < RPW; ++j) {
            float s1 = acc[j], s2 = acc[j] * acc[j];
            wave_sum2(s1, s2);
            const float mu  = s1 * (1.0f / 64.0f);
            const float var = s2 * (1.0f / 64.0f) - mu * mu;
            const float inv = rsqrtf(var + EPSF);
            const float lnv = g_f * ((acc[j] - mu) * inv) + be_f;
            const float gz  = 2.0f * (lnv - (xvr[j] - xkr[j]));
            sm.gz[p][w * RPW + j][f] = gz;
            gzp += gz;
        }
        sm.red[p][w][f] = gzp;

        // A = em * (xq @ xk^T), 16x16, one element per thread
        {
            const int kq = tid >> 4, kk = tid & 15;
            float a = 0.0f;
            #pragma unroll
            for (int i = 0; i < 16; ++i) {
                const float4 q4 = *(const float4*)&sm.xq[p][kq][4 * i];
                const float4 k4 = *(const float4*)&sm.xk[p][kk][4 * i];
                a = fmaf(q4.x, k4.x, a); a = fmaf(q4.y, k4.y, a);
                a = fmaf(q4.z, k4.z, a); a = fmaf(q4.w, k4.w, a);
            }
            sm.A[p][kq][kk] = em * a;
        }
        __syncthreads();                                   // B2

        // ---- R2: b1u = b1c - em*grad_b1 ----
        const float gb  = sm.red[p][0][f] + sm.red[p][1][f]
                        + sm.red[p][2][f] + sm.red[p][3][f];
        const float b1u = bb - em * gb;

        // Z1d = xq@W1c + b1u - A@gz   (== xq@W1u + b1u, exactly)
        float accd[RPW];
        #pragma unroll
        for (int j = 0; j < RPW; ++j) accd[j] = b1u;
        #pragma unroll
        for (int d = 0; d < 64; ++d) {
            const float wd = sm.Wsh[d][f];
            #pragma unroll
            for (int j = 0; j < RPW; ++j)
                accd[j] = fmaf(lane_bcast(xqr[j], d), wd, accd[j]);
        }
        #pragma unroll
        for (int kk = 0; kk < 16; ++kk) {
            const float gzv = sm.gz[p][kk][f];
            #pragma unroll
            for (int j = 0; j < RPW; ++j)
                accd[j] = fmaf(-sm.A[p][w * RPW + j][kk], gzv, accd[j]);
        }

        // out = xq + ln(Z1d)
        const int ob = base + t * 1024;
        #pragma unroll
        for (int j = 0; j < RPW; ++j) {
            float s1 = accd[j], s2 = accd[j] * accd[j];
            wave_sum2(s1, s2);
            const float mu  = s1 * (1.0f / 64.0f);
            const float var = s2 * (1.0f / 64.0f) - mu * mu;
            const float inv = rsqrtf(var + EPSF);
            const float lnv = g_f * ((accd[j] - mu) * inv) + be_f;
            OUT[ob + (w * RPW + j) * 64 + f] = xqr[j] + lnv;
        }
        __syncthreads();                                   // B3

        // ---- R3: carry rank-1 update W1 -= el * xk[15] (x) gz[15]; b1 update
        {
            const float gz15 = sm.gz[p][15][f];
            const float c = el * gz15;
            #pragma unroll
            for (int i = 0; i < 16; ++i) {
                const int d = w * 16 + i;
                sm.Wsh[d][f] = fmaf(-sm.xk[p][15][d], c, sm.Wsh[d][f]);
            }
            if (w == 0) sm.b1s[f] = bb - el * gz15;
        }
        __syncthreads();                                   // B4
    }
}

extern "C" void kernel_launch(void* const* d_in, const int* in_sizes, int n_in,
                              void* d_out, int out_size, void* d_ws, size_t ws_size,
                              hipStream_t stream) {
    const float* XQ    = (const float*)d_in[0];
    const float* XK    = (const float*)d_in[1];
    const float* XV    = (const float*)d_in[2];
    const float* W1    = (const float*)d_in[3];
    const float* b1    = (const float*)d_in[4];
    const float* gamma = (const float*)d_in[5];
    const float* beta  = (const float*)d_in[6];
    float* OUT = (float*)d_out;
    ttt_kernel<<<dim3(64), dim3(NTHREADS), 0, stream>>>(
        XQ, XK, XV, W1, b1, gamma, beta, OUT);
}